// Round 3
// baseline (273.318 us; speedup 1.0000x reference)
//
#include <hip/hip_runtime.h>
#include <math.h>

#define B_      16
#define K_      200000
#define N_      40
#define TPB     256
#define PAIRS   4
#define TILE    (TPB * PAIRS * 2)             // 2048 elements per block
#define NBX     ((K_ + TILE - 1) / TILE)      // 98
#define NE      (2 * N_)                      // 80 endpoints
#define NACC    7

// ws layout:
//   [0, 56)              : 7 double global accumulators (zeroed via hipMemsetAsync)
//   [64 + b*1024, ...)   : per-batch tables:
//       float bp[80]   @ +0      (sorted endpoints)
//       float stl[40]  @ +320    (area-sorted seg left)
//       float str[40]  @ +480    (area-sorted seg right)
//       float slb[40]  @ +640    (area-sorted seg label)
//       uchar w_at[80] @ +800    (winner when c == bp[i])
//       uchar w_gap[81]@ +880    (winner for open gap (bp[i-1], bp[i]))
#define TBL_OFF    64
#define TBL_STRIDE 1024

__global__ __launch_bounds__(256) void msl_setup(
    const float* __restrict__ targets, char* __restrict__ ws)
{
    __shared__ float tl0[N_], tr0[N_], lb0[N_], ar0[N_];
    __shared__ float stl[N_], str[N_], slb[N_];
    __shared__ float ep[NE], bp[NE];
    const int b = blockIdx.x, t = threadIdx.x;

    if (t < N_) {
        const float* tg = targets + (b * N_ + t) * 3;
        const float tl = tg[0], tr = tg[1];
        tl0[t] = tl; tr0[t] = tr; lb0[t] = tg[2];
        ar0[t] = (tr - tl) * 256.0f;
    }
    __syncthreads();

    // stable rank-sort segments by area (tie: original index) -> priority order
    if (t < N_) {
        const float an = ar0[t];
        int r = 0;
        #pragma unroll
        for (int m = 0; m < N_; ++m) {
            const float am = ar0[m];
            r += (am < an) || (am == an && m < t);
        }
        stl[r] = tl0[t]; str[r] = tr0[t]; slb[r] = lb0[t];
    }
    if (t < NE) ep[t] = (t < N_) ? tl0[t] : tr0[t - N_];
    __syncthreads();

    // sort endpoints
    if (t < NE) {
        const float v = ep[t];
        int r = 0;
        #pragma unroll
        for (int m = 0; m < NE; ++m) {
            const float vm = ep[m];
            r += (vm < v) || (vm == v && m < t);
        }
        bp[r] = v;
    }
    __syncthreads();

    char* tb = ws + TBL_OFF + b * TBL_STRIDE;
    float* tf = (float*)tb;

    // point winners: first (priority-order) segment with stl<=v<=str
    if (t < NE) {
        const float v = bp[t];
        int w = N_;
        for (int s = N_ - 1; s >= 0; --s)
            w = (stl[s] <= v && v <= str[s]) ? s : w;
        ((unsigned char*)(tb + 800))[t] = (unsigned char)w;
        tf[t] = v;                       // bp -> ws
    }
    // gap winners: open interval (a, bb) fully inside [stl,str]
    if (t >= 128 && t < 128 + NE + 1) {
        const int g = t - 128;           // 0..80
        const float a  = g ? bp[g - 1] : -INFINITY;
        const float bb = (g < NE) ? bp[g] : INFINITY;
        int w = N_;
        for (int s = N_ - 1; s >= 0; --s)
            w = (stl[s] <= a && bb <= str[s]) ? s : w;
        ((unsigned char*)(tb + 880))[g] = (unsigned char)w;
    }
    if (t < N_) {
        tf[80 + t]  = stl[t];
        tf[120 + t] = str[t];
        tf[160 + t] = slb[t];
    }
}

__global__ __launch_bounds__(TPB, 4) void msl_main(
    const float* __restrict__ loc,     // (B,K,2)
    const float* __restrict__ conf,    // (B,K,2)
    const float* __restrict__ ploc,    // (B,K,2)
    const float* __restrict__ pconf,   // (B,K,2)
    const float* __restrict__ center,  // (B,K,1)
    const float* __restrict__ priors,  // (K,1)
    char* __restrict__ ws)
{
    __shared__ float s_bp[128];
    __shared__ float s_stl[N_], s_str[N_], s_slb[N_];
    __shared__ unsigned char s_wat[80], s_wgap[84];
    __shared__ double s_red[TPB / 64][NACC];

    const int b = blockIdx.y;
    const int t = threadIdx.x;

    {
        const char* tb = ws + TBL_OFF + b * TBL_STRIDE;
        const float* tf = (const float*)tb;
        if (t < 80)              s_bp[t] = tf[t];
        else if (t < 128)        s_bp[t] = INFINITY;
        else if (t < 128 + 81)   s_wgap[t - 128] = ((const unsigned char*)(tb + 880))[t - 128];
        if (t >= 64 && t < 144)  s_wat[t - 64] = ((const unsigned char*)(tb + 800))[t - 64];
        if (t >= 144 && t < 184) s_stl[t - 144] = tf[80 + (t - 144)];
        if (t >= 184 && t < 224) s_str[t - 184] = tf[120 + (t - 184)];
        if (t >= 224)            s_slb[t - 224] = tf[160 + (t - 224)];
    }
    __syncthreads();

    const float EPS = 1.1920928955078125e-7f;  // FLT_EPSILON
    const int kb = blockIdx.x * TILE;
    const int bK2 = b * K_ * 2;   // fits int: 6.4M

    float f0 = 0.f, f1 = 0.f, f2 = 0.f, f3 = 0.f, f4 = 0.f, f5 = 0.f, f6 = 0.f;

    #pragma unroll
    for (int p = 0; p < PAIRS; ++p) {
        const int k0 = kb + (p * TPB + t) * 2;   // even
        if (k0 >= K_) continue;

        const float2 c2  = *(const float2*)(priors + k0);
        const float4 l4  = *(const float4*)(loc   + bK2 + k0 * 2);
        const float4 cf4 = *(const float4*)(conf  + bK2 + k0 * 2);
        const float4 pl4 = *(const float4*)(ploc  + bK2 + k0 * 2);
        const float4 pc4 = *(const float4*)(pconf + bK2 + k0 * 2);
        const float2 ct2 = *(const float2*)(center + b * K_ + k0);

        #pragma unroll
        for (int e = 0; e < 2; ++e) {
            const float c  = e ? c2.y  : c2.x;
            const float pl = e ? l4.z  : l4.x;
            const float pr = e ? l4.w  : l4.y;
            const float x0 = e ? cf4.z : cf4.x;
            const float x1 = e ? cf4.w : cf4.y;
            const float p0 = e ? pl4.z : pl4.x;
            const float p1 = e ? pl4.w : pl4.y;
            const float y0 = e ? pc4.z : pc4.x;
            const float y1 = e ? pc4.w : pc4.y;
            const float lg = e ? ct2.y : ct2.x;

            // ---- match via binary search over sorted endpoints ----
            int pos = 0;
            #pragma unroll
            for (int s = 64; s; s >>= 1)
                pos += (s_bp[pos + s - 1] <= c) ? s : 0;   // pos = #bp <= c, in [0,80]
            const int ia = pos ? pos - 1 : 0;
            const bool eq = pos && (s_bp[ia] == c);
            const int w = eq ? (int)s_wat[ia] : (int)s_wgap[pos];
            const bool dn = (w < N_);
            const int si = dn ? w : 0;

            const float tl = s_stl[si], tr = s_str[si];
            const float lt0 = (c - tl) * 256.0f;
            const float lt1 = (tr - c) * 256.0f;
            const int conf_t = dn ? (int)s_slb[si] : 0;

            // ---- iou(loc, loc_t) ----
            const float inter = fminf(pl, lt0) + fminf(pr, lt1);
            const float uni   = pl + pr + (lt0 + lt1) - inter;
            const float iou   = __fdividef(inter, fmaxf(uni, EPS));
            const int pconf_t = (iou < 0.5f) ? 0 : conf_t;

            const float posf = (conf_t > 0) ? 1.0f : 0.0f;
            const float ppf  = (pconf_t > 0) ? 1.0f : 0.0f;

            // GIoU (pos only)
            const float ac   = fmaxf(pl, lt0) + fmaxf(pr, lt1);
            const float giou = iou - __fdividef(ac - uni, fmaxf(ac, EPS));
            f0 += (1.0f - giou) * posf;

            // prop loc L1 (prop-pos only)
            const float prop_w = pl + pr;
            const float rw = __fdividef(1.0f, 0.5f * prop_w);
            const float plt0 = (lt0 - pl) * rw;
            const float plt1 = (lt1 - pr) * rw;
            f2 += (fabsf(p0 - plt0) + fabsf(p1 - plt1)) * ppf;

            // centerness BCE (pos only)
            const float cur0 = 0.5f * prop_w * p0 + pl;
            const float cur1 = 0.5f * prop_w * p1 + pr;
            const float inter2 = fminf(cur0, lt0) + fminf(cur1, lt1);
            const float uni2   = cur0 + cur1 + (lt0 + lt1) - inter2;
            const float iou2   = fmaxf(__fdividef(inter2, fmaxf(uni2, EPS)), 0.0f);
            const float bce = fmaxf(lg, 0.0f) - lg * iou2
                              + __logf(1.0f + __expf(-fabsf(lg)));
            f4 += bce * posf;

            // focal on conf (all)
            {
                const float xt = conf_t ? x1 : x0;
                const float xo = conf_t ? x0 : x1;
                const float pt = __fdividef(1.0f, 1.0f + __expf(xo - xt)) + 1e-6f;
                const float al = conf_t ? 0.75f : 0.25f;
                const float om = 1.0f - pt;
                f1 += -om * om * al * __logf(pt);
            }
            // focal on prop_conf (all)
            {
                const float xt = pconf_t ? y1 : y0;
                const float xo = pconf_t ? y0 : y1;
                const float pt = __fdividef(1.0f, 1.0f + __expf(xo - xt)) + 1e-6f;
                const float al = pconf_t ? 0.75f : 0.25f;
                const float om = 1.0f - pt;
                f3 += -om * om * al * __logf(pt);
            }

            f5 += posf;
            f6 += ppf;
        }
    }

    // ---- block reduction, then one atomicAdd per accumulator ----
    double vals[NACC] = {(double)f0, (double)f1, (double)f2, (double)f3,
                         (double)f4, (double)f5, (double)f6};
    const int wave = t >> 6, lane = t & 63;
    #pragma unroll
    for (int q = 0; q < NACC; ++q) {
        double v = vals[q];
        #pragma unroll
        for (int off = 32; off > 0; off >>= 1)
            v += __shfl_down(v, off, 64);
        if (lane == 0) s_red[wave][q] = v;
    }
    __syncthreads();
    if (t == 0) {
        double* gacc = (double*)ws;
        #pragma unroll
        for (int q = 0; q < NACC; ++q) {
            double s = 0.0;
            #pragma unroll
            for (int w2 = 0; w2 < TPB / 64; ++w2) s += s_red[w2][q];
            atomicAdd(&gacc[q], s);
        }
    }
}

__global__ __launch_bounds__(64) void msl_final(
    const double* __restrict__ gacc, float* __restrict__ out)
{
    if (threadIdx.x == 0) {
        const double Np = fmax(gacc[5], 1.0);
        const double PN = fmax(gacc[6], 1.0);
        out[0] = (float)(gacc[0] / Np);
        out[1] = (float)(gacc[1] / Np);
        out[2] = (float)(gacc[2] / PN);
        out[3] = (float)(gacc[3] / PN);
        out[4] = (float)(gacc[4] / Np);
    }
}

extern "C" void kernel_launch(void* const* d_in, const int* in_sizes, int n_in,
                              void* d_out, int out_size, void* d_ws, size_t ws_size,
                              hipStream_t stream) {
    const float* loc     = (const float*)d_in[0];
    const float* conf    = (const float*)d_in[1];
    const float* ploc    = (const float*)d_in[2];
    const float* pconf   = (const float*)d_in[3];
    const float* center  = (const float*)d_in[4];
    const float* priors  = (const float*)d_in[5];
    const float* targets = (const float*)d_in[6];
    char* ws = (char*)d_ws;   // uses 64 + 16*1024 = 16,448 bytes

    hipMemsetAsync(ws, 0, 64, stream);   // zero the 7 double accumulators
    msl_setup<<<B_, 256, 0, stream>>>(targets, ws);
    dim3 grid(NBX, B_);
    msl_main<<<grid, TPB, 0, stream>>>(loc, conf, ploc, pconf, center, priors, ws);
    msl_final<<<1, 64, 0, stream>>>((const double*)ws, (float*)d_out);
}